// Round 4
// baseline (506.704 us; speedup 1.0000x reference)
//
#include <hip/hip_runtime.h>
#include <stdint.h>
#include <stddef.h>

#define B_ 8
#define N_ 2048
#define C_ 2048
#define D_ 256
#define H_ 256

typedef __bf16 bf16x8 __attribute__((ext_vector_type(8)));
typedef __bf16 bf16x4 __attribute__((ext_vector_type(4)));
typedef float f32x4 __attribute__((ext_vector_type(4)));

#define MFMA16(a, b, c) __builtin_amdgcn_mfma_f32_16x16x32_bf16((a), (b), (c), 0, 0, 0)

// ---------------------------------------------------------------------------
// K0a/K0b: collapse score projections to vectors, parallelized over h-chunks.
// ---------------------------------------------------------------------------
__global__ __launch_bounds__(256) void k0a_partial(
    const float* __restrict__ oma_q_w, const float* __restrict__ oma_kv_w,
    const float* __restrict__ sa_w_w,
    const float* __restrict__ oma_s_w, const float* __restrict__ sa_s_w,
    float* __restrict__ partial)
{
    int d = threadIdx.x;
    int vec = blockIdx.x >> 3, hc = blockIdx.x & 7;
    int h0 = hc * 32;
    const float* Wb; const float* sv;
    if (vec == 0)      { Wb = oma_q_w  + h0 * 256;         sv = oma_s_w + h0; }
    else if (vec == 1) { Wb = oma_kv_w + h0 * 256;         sv = oma_s_w + 256 + h0; }
    else if (vec == 2) { Wb = sa_w_w   + h0 * 256;         sv = sa_s_w + h0; }
    else               { Wb = sa_w_w   + (256 + h0) * 256; sv = sa_s_w + 256 + h0; }
    float a = 0.f;
    #pragma unroll 8
    for (int h = 0; h < 32; ++h) a += Wb[h * 256 + d] * sv[h];
    partial[blockIdx.x * 256 + d] = a;
}

__global__ __launch_bounds__(256) void k0b_reduce(
    const float* __restrict__ partial,
    const float* __restrict__ oma_q_b, const float* __restrict__ oma_kv_b,
    const float* __restrict__ oma_s_w, const float* __restrict__ oma_s_b,
    const float* __restrict__ sa_w_b, const float* __restrict__ sa_s_w,
    const float* __restrict__ sa_s_b,
    float* __restrict__ wq_v, float* __restrict__ wk_v,
    float* __restrict__ wq2_v, float* __restrict__ wk2_v,
    float* __restrict__ sb)
{
    int d = threadIdx.x;
    float a0 = 0.f, a1 = 0.f, a2 = 0.f, a3 = 0.f;
    #pragma unroll
    for (int hc = 0; hc < 8; ++hc) {
        a0 += partial[(0 * 8 + hc) * 256 + d];
        a1 += partial[(1 * 8 + hc) * 256 + d];
        a2 += partial[(2 * 8 + hc) * 256 + d];
        a3 += partial[(3 * 8 + hc) * 256 + d];
    }
    wq_v[d] = a0; wk_v[d] = a1; wq2_v[d] = a2; wk2_v[d] = a3;

    int h = d;
    float p1 = oma_q_b[h] * oma_s_w[h] + oma_kv_b[h] * oma_s_w[256 + h];
    float p2 = sa_w_b[h] * sa_s_w[h] + sa_w_b[256 + h] * sa_s_w[256 + h];
    for (int o = 32; o; o >>= 1) { p1 += __shfl_xor(p1, o); p2 += __shfl_xor(p2, o); }
    __shared__ float redA[4], redB[4];
    int wv = threadIdx.x >> 6;
    if ((threadIdx.x & 63) == 0) { redA[wv] = p1; redB[wv] = p2; }
    __syncthreads();
    if (threadIdx.x == 0) {
        sb[0] = redA[0] + redA[1] + redA[2] + redA[3] + oma_s_b[0];
        sb[1] = redB[0] + redB[1] + redB[2] + redB[3] + sa_s_b[0];
    }
}

// ---------------------------------------------------------------------------
// K1: fold output projections through mix.
// ---------------------------------------------------------------------------
__global__ __launch_bounds__(256) void k1_wcat(
    const float* __restrict__ mix_w, const float* __restrict__ mix_b,
    const float* __restrict__ oma_o_w, const float* __restrict__ oma_o_b,
    const float* __restrict__ sa_o_w, const float* __restrict__ sa_o_b,
    __bf16* __restrict__ Wcat, float* __restrict__ b_total)
{
    int d = blockIdx.x, h = threadIdx.x;
    const float* mwr = mix_w + d * 512;
    float w1 = 0.f, w2 = 0.f;
    #pragma unroll 4
    for (int e = 0; e < 256; ++e) {
        w1 += mwr[e] * oma_o_w[e * 256 + h];
        w2 += mwr[256 + e] * sa_o_w[e * 256 + h];
    }
    Wcat[d * 512 + h] = (__bf16)w1;
    Wcat[d * 512 + 256 + h] = (__bf16)w2;

    float pb = mwr[h] * oma_o_b[h] + mwr[256 + h] * sa_o_b[h];
    for (int o = 32; o; o >>= 1) pb += __shfl_xor(pb, o);
    __shared__ float red[4];
    if ((h & 63) == 0) red[h >> 6] = pb;
    __syncthreads();
    if (h == 0) b_total[d] = mix_b[d] + red[0] + red[1] + red[2] + red[3];
}

// ---------------------------------------------------------------------------
// K2: per-row score scalars (unchanged).
// ---------------------------------------------------------------------------
__global__ __launch_bounds__(256) void k2_scores(
    const float* __restrict__ op, const float* __restrict__ mach,
    const float* __restrict__ wq_v, const float* __restrict__ wk_v,
    const float* __restrict__ wq2_v, const float* __restrict__ wk2_v,
    const float* __restrict__ sb,
    float* __restrict__ sqp, float* __restrict__ skv,
    float* __restrict__ sq2p, float* __restrict__ sk2v)
{
    int t = threadIdx.x, lane = t & 63, wv = t >> 6;
    size_t n = (size_t)blockIdx.x * 4 + wv;
    const float4 mf = *(const float4*)(mach + n * 256 + lane * 4);
    const float4 of = *(const float4*)(op + n * 256 + lane * 4);
    const float4 q4 = *(const float4*)(wq_v + lane * 4);
    const float4 k4 = *(const float4*)(wk_v + lane * 4);
    const float4 q24 = *(const float4*)(wq2_v + lane * 4);
    const float4 k24 = *(const float4*)(wk2_v + lane * 4);
    float s1 = mf.x * q4.x + mf.y * q4.y + mf.z * q4.z + mf.w * q4.w;
    float s2 = of.x * k4.x + of.y * k4.y + of.z * k4.z + of.w * k4.w;
    float s3 = mf.x * q24.x + mf.y * q24.y + mf.z * q24.z + mf.w * q24.w;
    float s4 = mf.x * k24.x + mf.y * k24.y + mf.z * k24.z + mf.w * k24.w;
    for (int o = 32; o; o >>= 1) {
        s1 += __shfl_xor(s1, o); s2 += __shfl_xor(s2, o);
        s3 += __shfl_xor(s3, o); s4 += __shfl_xor(s4, o);
    }
    if (lane == 0) {
        sqp[n] = s1 + sb[0]; skv[n] = s2;
        sq2p[n] = s3 + sb[1]; sk2v[n] = s4;
    }
}

// ---------------------------------------------------------------------------
// K3: value projections, TRANSPOSED output vt[which][b][h][c] (unchanged).
// ---------------------------------------------------------------------------
__global__ __launch_bounds__(256, 2) void k3_vgemm(
    const float* __restrict__ op, const float* __restrict__ mach,
    const float* __restrict__ oma_kv_w, const float* __restrict__ sa_w_w,
    __bf16* __restrict__ vt)
{
    __shared__ __attribute__((aligned(16))) __bf16 As[64][72];
    __shared__ __attribute__((aligned(16))) __bf16 Bs[64][72];
    int t = threadIdx.x;
    int bid = blockIdx.x;
    int which = bid >> 10;
    int r = bid & 1023;
    int b = r >> 7;
    int ht = (r >> 5) & 3;
    int ct = r & 31;

    const float* Aglob = (which ? (sa_w_w + 512 * 256) : (oma_kv_w + 256 * 256)) + ht * 64 * 256;
    const float* Bglob = (which ? mach : op) + ((size_t)b * N_ + ct * 64) * 256;

    int lane = t & 63, wv = t >> 6;
    int l15 = lane & 15, qo = (lane >> 4) * 8;
    int rr = t >> 4;
    int dd = (t & 15) * 4;

    f32x4 acc[4] = {};

    for (int d0 = 0; d0 < 256; d0 += 64) {
        #pragma unroll
        for (int p = 0; p < 4; ++p) {
            float4 av = *(const float4*)(Aglob + (size_t)(p * 16 + rr) * 256 + d0 + dd);
            float4 bv = *(const float4*)(Bglob + (size_t)(p * 16 + rr) * 256 + d0 + dd);
            bf16x4 a4, b4;
            a4[0] = (__bf16)av.x; a4[1] = (__bf16)av.y; a4[2] = (__bf16)av.z; a4[3] = (__bf16)av.w;
            b4[0] = (__bf16)bv.x; b4[1] = (__bf16)bv.y; b4[2] = (__bf16)bv.z; b4[3] = (__bf16)bv.w;
            *(bf16x4*)&As[p * 16 + rr][dd] = a4;
            *(bf16x4*)&Bs[p * 16 + rr][dd] = b4;
        }
        __syncthreads();
        #pragma unroll
        for (int kb = 0; kb < 2; ++kb) {
            bf16x8 bfr = *(const bf16x8*)&Bs[16 * wv + l15][kb * 32 + qo];
            #pragma unroll
            for (int rt = 0; rt < 4; ++rt) {
                bf16x8 afr = *(const bf16x8*)&As[16 * rt + l15][kb * 32 + qo];
                acc[rt] = MFMA16(afr, bfr, acc[rt]);
            }
        }
        __syncthreads();
    }
    #pragma unroll
    for (int rt = 0; rt < 4; ++rt)
        #pragma unroll
        for (int j = 0; j < 4; ++j)
            As[16 * rt + (lane >> 4) * 4 + j][16 * wv + l15] = (__bf16)acc[rt][j];
    __syncthreads();
    int hh = t >> 2, cb = (t & 3) * 16;
    __bf16* orow = vt + (((size_t)(which * 8 + b)) * 256 + ht * 64 + hh) * 2048 + ct * 64 + cb;
    *(bf16x8*)(orow) = *(const bf16x8*)&As[hh][cb];
    *(bf16x8*)(orow + 8) = *(const bf16x8*)&As[hh][cb + 8];
}

// ---------------------------------------------------------------------------
// K4 v5: fat-block c-split attention.
//   512 threads: waves 0-3 process c in [0,1024), waves 4-7 c in [1024,2048).
//   -> 16 chunks (serial barriers halved), 16 waves/CU, V/mask traffic
//      unchanged vs the 64-row 256-thread version.
//   Phase A: contiguous mask stream (4KB/wave-instr bursts, NT) -> 1-bit LDS
//     table Mb. Exact: mask in {0,1}, exp(s*m) == bit ? exp(s) : 1.
//   Loop: reg-direct V from L2, double-buffered e-tile, sk from LDS table,
//     ONE raw barrier per chunk (lgkmcnt asm + s_barrier; NO vmcnt drains).
//   Epilogue: halves combine acc + rowsum through LDS (2 passes of 32 rows).
// ---------------------------------------------------------------------------
__device__ __forceinline__ f32x4 ntload4f(const float* p) {
    return __builtin_nontemporal_load(reinterpret_cast<const f32x4*>(p));
}

__global__ __launch_bounds__(512, 4) void k4_attn(
    const float* __restrict__ tmask, const float* __restrict__ smask,
    const float* __restrict__ sqp, const float* __restrict__ skv,
    const float* __restrict__ sq2p, const float* __restrict__ sk2v,
    const __bf16* __restrict__ vt,
    __bf16* __restrict__ wfcat)
{
    // layout: eA[2 half][2 dbuf][64][72] bf16 @0 (36864B)
    //         Mb u16[64*130]              @36864 (16640B)
    //         skL f32[2048]               @53504 (8192B)
    //         rowsumH f32[2][64]          @61696 (512B)
    //         fbuf f32[32][260] aliases eA region in epilogue (33280B)
    __shared__ __attribute__((aligned(16))) unsigned char smem[62208];
    __bf16* eAll = (__bf16*)smem;
    uint16_t* Mb = (uint16_t*)(smem + 36864);
    float* skL = (float*)(smem + 53504);
    float* rowsumH = (float*)(smem + 61696);
    float* fbuf = (float*)smem;

    int t = threadIdx.x;
    int bid = blockIdx.x;
    int wg = (bid & 7) * 64 + (bid >> 3);   // bijective: 512 = 8 XCD x 64
    int which = wg >> 8;
    int r = wg & 255;
    int b = r >> 5;
    int m0 = (r & 31) * 64;

    const float* mask = (which ? smask : tmask) + ((size_t)b * N_ + m0) * C_;
    const float* sqrow = (which ? sq2p : sqp) + b * N_ + m0;
    const float* skrow = (which ? sk2v : skv) + b * N_;
    const __bf16* vbase = vt + ((size_t)(which * 8 + b)) * 256 * 2048;

    int half = t >> 8;          // 0: c 0..1023, 1: c 1024..2047
    int tl = t & 255;
    int lane = tl & 63, wv4 = tl >> 6;
    int l15 = lane & 15, qo = (lane >> 4) * 8;
    int mrow = tl >> 2;         // 0..63
    int cq16 = (tl & 3) * 16;   // 16-col slice within a 64-chunk

    const __bf16* vptr = vbase + (size_t)(64 * wv4 + l15) * 2048 + half * 1024 + qo;
    __bf16* eH0 = eAll + (half * 2 + 0) * 4608;
    __bf16* eH1 = eAll + (half * 2 + 1) * 4608;

    float sqv = sqrow[mrow];
    float psum = 0.f;
    f32x4 acc[4][4] = {};
    bf16x8 vv[8];

    auto load_v = [&](int c0) {   // c0 in [0,1024) within this half
        #pragma unroll
        for (int ct = 0; ct < 4; ++ct)
            #pragma unroll
            for (int kb = 0; kb < 2; ++kb)
                vv[ct * 2 + kb] = *(const bf16x8*)(vptr + (size_t)ct * 16 * 2048 + c0 + kb * 32);
    };

    load_v(0);                                   // V(0) in flight during phase A
    *(f32x4*)(skL + t * 4) = *(const f32x4*)(skrow + t * 4);   // sk table

    // ---- phase A: contiguous mask stream -> bit table ----
    {
        int col16 = t & 127;     // u16 column
        int rg = t >> 7;         // 0..3
        const float* mp = mask + (size_t)rg * C_ + col16 * 16;
        uint16_t* mbp = Mb + rg * 130 + col16;
        #pragma unroll 4
        for (int i = 0; i < 16; ++i) {
            const float* p = mp + (size_t)i * 4 * C_;
            f32x4 a = ntload4f(p);
            f32x4 bq = ntload4f(p + 4);
            f32x4 cq = ntload4f(p + 8);
            f32x4 dq = ntload4f(p + 12);
            uint32_t bits = 0;
            #pragma unroll
            for (int j = 0; j < 4; ++j) {
                bits |= (a[j]  != 0.f ? 1u : 0u) << j;
                bits |= (bq[j] != 0.f ? 1u : 0u) << (4 + j);
                bits |= (cq[j] != 0.f ? 1u : 0u) << (8 + j);
                bits |= (dq[j] != 0.f ? 1u : 0u) << (12 + j);
            }
            mbp[i * 4 * 130] = (uint16_t)bits;
        }
    }
    __syncthreads();   // the only full drain in the kernel body

    const float* skLp = skL + half * 1024 + cq16;
    const uint16_t* mbq = Mb + mrow * 130 + half * 64 + (tl & 3);

    auto compute_e = [&](int c0, __bf16* eb) {
        uint32_t mbits = mbq[c0 >> 4];
        f32x4 sk0 = *(const f32x4*)(skLp + c0);
        f32x4 sk1 = *(const f32x4*)(skLp + c0 + 4);
        f32x4 sk2 = *(const f32x4*)(skLp + c0 + 8);
        f32x4 sk3 = *(const f32x4*)(skLp + c0 + 12);
        float sk[16];
        #pragma unroll
        for (int j = 0; j < 4; ++j) {
            sk[j] = sk0[j]; sk[4 + j] = sk1[j]; sk[8 + j] = sk2[j]; sk[12 + j] = sk3[j];
        }
        bf16x8 e0, e1;
        #pragma unroll
        for (int i = 0; i < 16; ++i) {
            float s = sqv + sk[i];
            s = s > 0.f ? s : 0.01f * s;
            float e = (mbits & (1u << i)) ? __expf(s) : 1.0f;
            psum += e;
            if (i < 8) e0[i] = (__bf16)e; else e1[i - 8] = (__bf16)e;
        }
        *(bf16x8*)&eb[mrow * 72 + cq16] = e0;
        *(bf16x8*)&eb[mrow * 72 + cq16 + 8] = e1;
    };
    auto do_mfma = [&](const __bf16* eb) {
        #pragma unroll
        for (int kb = 0; kb < 2; ++kb) {
            bf16x8 afr[4];
            #pragma unroll
            for (int rt = 0; rt < 4; ++rt)
                afr[rt] = *(const bf16x8*)&eb[(16 * rt + l15) * 72 + kb * 32 + qo];
            #pragma unroll
            for (int ct = 0; ct < 4; ++ct)
                #pragma unroll
                for (int rt = 0; rt < 4; ++rt)
                    acc[rt][ct] = MFMA16(afr[rt], vv[ct * 2 + kb], acc[rt][ct]);
        }
    };

    #pragma unroll 1
    for (int it = 0; it < 8; ++it) {
        int cE = it * 128, cO = cE + 64;
        // even chunk -> buf 0
        compute_e(cE, eH0);
        asm volatile("s_waitcnt lgkmcnt(0)" ::: "memory");
        __builtin_amdgcn_s_barrier();
        do_mfma(eH0);                 // vv == V(cE)
        load_v(cO);                   // V(cO): lands during next e-compute
        // odd chunk -> buf 1
        compute_e(cO, eH1);
        asm volatile("s_waitcnt lgkmcnt(0)" ::: "memory");
        __builtin_amdgcn_s_barrier();
        do_mfma(eH1);                 // vv == V(cO)
        load_v((cE + 128) & 1023);    // V(next even); wraps harmlessly at end
    }

    // ---- epilogue: combine halves, normalize, store ----
    float rs = psum;
    rs += __shfl_xor(rs, 1);
    rs += __shfl_xor(rs, 2);
    if ((tl & 3) == 0) rowsumH[half * 64 + mrow] = rs;
    __syncthreads();

    #pragma unroll
    for (int p = 0; p < 2; ++p) {
        if (half == 1) {
            #pragma unroll
            for (int rr2 = 0; rr2 < 2; ++rr2) {
                int rt = 2 * p + rr2;
                #pragma unroll
                for (int ct = 0; ct < 4; ++ct)
                    #pragma unroll
                    for (int j = 0; j < 4; ++j) {
                        int ml = 16 * rr2 + (lane >> 4) * 4 + j;
                        fbuf[ml * 260 + 64 * wv4 + 16 * ct + l15] = acc[rt][ct][j];
                    }
            }
        }
        __syncthreads();
        if (half == 0) {
            #pragma unroll
            for (int rr2 = 0; rr2 < 2; ++rr2) {
                int rt = 2 * p + rr2;
                #pragma unroll
                for (int j = 0; j < 4; ++j) {
                    int ml = 16 * rr2 + (lane >> 4) * 4 + j;
                    int m = 32 * p + ml;
                    float inv = __builtin_amdgcn_rcpf(rowsumH[m] + rowsumH[64 + m]);
                    #pragma unroll
                    for (int ct = 0; ct < 4; ++ct) {
                        int cc = 64 * wv4 + 16 * ct + l15;
                        fbuf[ml * 260 + cc] = (acc[rt][ct][j] + fbuf[ml * 260 + cc]) * inv;
                    }
                }
            }
        }
        __syncthreads();
        {
            int row = t >> 4, c16 = (t & 15) * 16;
            const float* fr = fbuf + row * 260 + c16;
            bf16x8 o0, o1;
            #pragma unroll
            for (int k = 0; k < 8; ++k) { o0[k] = (__bf16)fr[k]; o1[k] = (__bf16)fr[8 + k]; }
            __bf16* wrow = wfcat + ((size_t)(b * N_ + m0 + 32 * p + row)) * 512 + which * 256 + c16;
            *(bf16x8*)wrow = o0;
            *(bf16x8*)(wrow + 8) = o1;
        }
        __syncthreads();
    }
}

// ---------------------------------------------------------------------------
// K5: out[n][d] = wfcat[n][:512] . Wcat[d][:512] + b_total[d]
// ---------------------------------------------------------------------------
__global__ __launch_bounds__(256, 2) void k5_out(
    const __bf16* __restrict__ wfcat, const __bf16* __restrict__ Wcat,
    const float* __restrict__ b_total, float* __restrict__ out)
{
    __shared__ __attribute__((aligned(16))) __bf16 As[32][72];
    __shared__ __attribute__((aligned(16))) __bf16 Bs[256][72];
    __shared__ float bias[256];
    int t = threadIdx.x;
    int n0 = blockIdx.x * 32;
    int lane = t & 63, wv = t >> 6, l15 = lane & 15, qo = (lane >> 4) * 8;
    bias[t] = b_total[t];
    int ar = t >> 3;
    int ac = (t & 7) * 8;
    f32x4 acc[2][4] = {};

    for (int k0 = 0; k0 < 512; k0 += 64) {
        *(bf16x8*)&As[ar][ac] =
            *(const bf16x8*)(wfcat + (size_t)(n0 + ar) * 512 + k0 + ac);
        #pragma unroll
        for (int p = 0; p < 8; ++p)
            *(bf16x8*)&Bs[p * 32 + ar][ac] =
                *(const bf16x8*)(Wcat + (size_t)(p * 32 + ar) * 512 + k0 + ac);
        __syncthreads();
        #pragma unroll
        for (int kb = 0; kb < 2; ++kb) {
            bf16x8 afr[2];
            #pragma unroll
            for (int rt = 0; rt < 2; ++rt)
                afr[rt] = *(const bf16x8*)&As[16 * rt + l15][kb * 32 + qo];
            #pragma unroll
            for (int ct = 0; ct < 4; ++ct) {
                bf16x8 bfr = *(const bf16x8*)&Bs[64 * wv + 16 * ct + l15][kb * 32 + qo];
                #pragma unroll
                for (int rt = 0; rt < 2; ++rt)
                    acc[rt][ct] = MFMA16(afr[rt], bfr, acc[rt][ct]);
            }
        }
        __syncthreads();
    }
    #pragma unroll
    for (int rt = 0; rt < 2; ++rt) {
        #pragma unroll
        for (int ct = 0; ct < 4; ++ct) {
            int d = 64 * wv + 16 * ct + l15;
            float bv = bias[d];
            #pragma unroll
            for (int j = 0; j < 4; ++j) {
                int m = 16 * rt + (lane >> 4) * 4 + j;
                out[(size_t)(n0 + m) * 256 + d] = acc[rt][ct][j] + bv;
            }
        }
    }
}

// ---------------------------------------------------------------------------
extern "C" void kernel_launch(void* const* d_in, const int* in_sizes, int n_in,
                              void* d_out, int out_size, void* d_ws, size_t ws_size,
                              hipStream_t stream)
{
    const float* op_feat  = (const float*)d_in[0];
    const float* mach_feat= (const float*)d_in[1];
    const float* tmask    = (const float*)d_in[2];
    const float* smask    = (const float*)d_in[3];
    const float* oma_q_w  = (const float*)d_in[4];
    const float* oma_q_b  = (const float*)d_in[5];
    const float* oma_kv_w = (const float*)d_in[6];
    const float* oma_kv_b = (const float*)d_in[7];
    const float* oma_s_w  = (const float*)d_in[8];
    const float* oma_s_b  = (const float*)d_in[9];
    const float* oma_o_w  = (const float*)d_in[10];
    const float* oma_o_b  = (const float*)d_in[11];
    const float* sa_w_w   = (const float*)d_in[12];
    const float* sa_w_b   = (const float*)d_in[13];
    const float* sa_s_w   = (const float*)d_in[14];
    const float* sa_s_b   = (const float*)d_in[15];
    const float* sa_o_w   = (const float*)d_in[16];
    const float* sa_o_b   = (const float*)d_in[17];
    const float* mix_w    = (const float*)d_in[18];
    const float* mix_b    = (const float*)d_in[19];

    char* ws = (char*)d_ws;
    float* wq_v   = (float*)(ws + 0);
    float* wk_v   = (float*)(ws + 1024);
    float* wq2_v  = (float*)(ws + 2048);
    float* wk2_v  = (float*)(ws + 3072);
    float* sb     = (float*)(ws + 4096);
    float* btot   = (float*)(ws + 4352);
    float* sqp    = (float*)(ws + 8192);
    float* skv    = (float*)(ws + 73728);
    float* sq2p   = (float*)(ws + 139264);
    float* sk2v   = (float*)(ws + 204800);
    __bf16* Wcat  = (__bf16*)(ws + 270336);    //  256 KB
    __bf16* vt    = (__bf16*)(ws + 532480);    //   16 MB : [2][8][256][2048]
    __bf16* wfcat = (__bf16*)(ws + 17309696);  //   16 MB : [16384][512]
    float* outp   = (float*)d_out;

    float* partial = (float*)(ws + 532480);    // 32 KB, overwritten by k3 later

    k0a_partial<<<32, 256, 0, stream>>>(oma_q_w, oma_kv_w, sa_w_w,
                                        oma_s_w, sa_s_w, partial);
    k0b_reduce<<<1, 256, 0, stream>>>(partial, oma_q_b, oma_kv_b, oma_s_w, oma_s_b,
                                      sa_w_b, sa_s_w, sa_s_b,
                                      wq_v, wk_v, wq2_v, wk2_v, sb);
    k1_wcat<<<256, 256, 0, stream>>>(mix_w, mix_b, oma_o_w, oma_o_b,
                                     sa_o_w, sa_o_b, Wcat, btot);
    k2_scores<<<4096, 256, 0, stream>>>(op_feat, mach_feat, wq_v, wk_v, wq2_v, wk2_v,
                                        sb, sqp, skv, sq2p, sk2v);
    k3_vgemm<<<2048, 256, 0, stream>>>(op_feat, mach_feat, oma_kv_w, sa_w_w, vt);
    k4_attn<<<512, 512, 0, stream>>>(tmask, smask, sqp, skv, sq2p, sk2v, vt, wfcat);
    k5_out<<<512, 256, 0, stream>>>(wfcat, Wcat, btot, outp);
}